// Round 4
// baseline (314.241 us; speedup 1.0000x reference)
//
#include <hip/hip_runtime.h>
#include <hip/hip_fp16.h>

#define M_DIM 16384
#define K_DIM 2048
#define N_DIM 2048
#define KSEG  (K_DIM / 64)     // 32 k-segments per 32-row block

#define BM 128
#define BN 256
#define BK 64

typedef int int4v  __attribute__((ext_vector_type(4)));
typedef int int16v __attribute__((ext_vector_type(16)));

__device__ __forceinline__ void gl_lds16(const void* g, void* l) {
    __builtin_amdgcn_global_load_lds(
        (const __attribute__((address_space(1))) void*)g,
        (__attribute__((address_space(3))) void*)l,
        16, 0, 0);
}

__device__ __forceinline__ int pack4(int4v v) {
    return (v[0] & 255) | ((v[1] & 255) << 8) | ((v[2] & 255) << 16) | (v[3] << 24);
}

// ---- Tiled ("MFMA-native") global layout for both operands ----
// unit u = rowblk * KSEG + kseg   (rowblk = 32 rows, kseg = 64 K-bytes), 2 KB/unit
// within unit: slot tt = (ks*2+kh)*32 + r  holds X[rowblk*32+r][kseg*64 + ks*32 + kh*16 .. +16]
// => GEMM staging is contiguous in global AND slot-linear in LDS;
// => fragment ds_read_b128 is lane-linear (R1 pattern, measured 0 conflicts).

// x: int32 [M,K] -> A_t tiled int8. One block = 2 units (4 KB out, 16 KB in).
__global__ void pack_x_kernel(const int* __restrict__ x, char* __restrict__ at) {
    int t = threadIdx.x;
    int u = blockIdx.x * 2 + (t >> 7);
    int tt = t & 127;
    int mblk = u >> 5, kseg = u & 31;
    int r = tt & 31;
    int kin = ((tt >> 5) & 3) * 16;    // (ks*2+kh)*16
    // input: 16 consecutive int32 (64 B); lane l & l+32 share each 128B line fully
    const int4v* src = (const int4v*)(x + (size_t)(mblk * 32 + r) * K_DIM + kseg * 64 + kin);
    int4v o;
    o[0] = pack4(src[0]); o[1] = pack4(src[1]); o[2] = pack4(src[2]); o[3] = pack4(src[3]);
    ((int4v*)at)[blockIdx.x * 256 + t] = o;   // fully linear 16B/lane store
}

// weight: int32 [K,N] -> B_t tiled int8 (transpose via LDS), 64x64 input tiles
__global__ void wt_pack_kernel(const int* __restrict__ w, char* __restrict__ bt) {
    __shared__ char tile[64][68];
    int b  = blockIdx.x;             // 32 (k) x 32 (n) tiles
    int k0 = (b & 31) * 64;
    int n0 = (b >> 5) * 64;
    int t  = threadIdx.x;
    int r  = t >> 2;
    int c  = (t & 3) * 16;

    const int* src = w + (size_t)(k0 + r) * N_DIM + n0 + c;
    int4v a = *(const int4v*)(src + 0);
    int4v bb = *(const int4v*)(src + 4);
    int4v cc = *(const int4v*)(src + 8);
    int4v dd = *(const int4v*)(src + 12);
    *(int*)&tile[r][c + 0]  = pack4(a);
    *(int*)&tile[r][c + 4]  = pack4(bb);
    *(int*)&tile[r][c + 8]  = pack4(cc);
    *(int*)&tile[r][c + 12] = pack4(dd);
    __syncthreads();

    char buf[16];
#pragma unroll
    for (int j = 0; j < 16; ++j) buf[j] = tile[c + j][r];
    // buf = 16 consecutive K-bytes (k0+c..) of column n0+r  ->  one tile slot
    int n = n0 + r;
    int nblk = n >> 5, r31 = n & 31;
    int kseg = k0 >> 6;
    int sl = (c >> 4) * 32 + r31;    // (ks*2+kh) = c/16
    *(int4v*)(bt + ((size_t)(nblk * KSEG + kseg) * 128 + sl) * 16) = *(int4v*)buf;
}

// GEMM: A_t tiled int8, B_t tiled int8 -> C fp32 [M,N] (+bias)
// 512 thr = 8 waves (2m x 4n); 128x256 tile; BK=64; wave = 64x64 = 2x2 of 32x32x32 MFMA.
// LDS: Asm 512 slots (8 KB), Bsm 1024 slots (16 KB); slot-linear staging, lane-linear reads.
__global__ __launch_bounds__(512, 4)
void gemm_i8_kernel(const char* __restrict__ A, const char* __restrict__ BT,
                    const __half* __restrict__ bias, float* __restrict__ C) {
    __shared__ char Asm[BM * BK];    // 8192 B
    __shared__ char Bsm[BN * BK];    // 16384 B

    int bid = blockIdx.x;
    int mt = bid & 127;              // m fastest: A-sharers same XCD, B-sharers adjacent
    int nt = bid >> 7;
    int R0 = mt * BM, C0 = nt * BN;

    int t = threadIdx.x;
    int lane = t & 63;
    int w = t >> 6;
    int wm = w & 1, wn = w >> 1;     // 2m x 4n wave grid

    int16v acc[2][2];
#pragma unroll
    for (int i = 0; i < 2; ++i)
#pragma unroll
        for (int j = 0; j < 2; ++j) acc[i][j] = (int16v)0;

    // staging global offsets (byte index, +it*2048 per iter)
    unsigned abase  = (unsigned)((R0 >> 5) + (t >> 7)) * (KSEG * 2048) + (t & 127) * 16;
    unsigned bbase0 = (unsigned)((C0 >> 5) + (t >> 7)) * (KSEG * 2048) + (t & 127) * 16;
    unsigned bbase1 = (unsigned)((C0 >> 5) + (t >> 7) + 4) * (KSEG * 2048) + (t & 127) * 16;

    for (int it = 0; it < K_DIM / BK; ++it) {
        unsigned ko = it * 2048;
        gl_lds16(A + abase + ko,   &Asm[t * 16]);
        gl_lds16(BT + bbase0 + ko, &Bsm[t * 16]);
        gl_lds16(BT + bbase1 + ko, &Bsm[(t + 512) * 16]);
        __syncthreads();

#pragma unroll
        for (int ks = 0; ks < 2; ++ks) {
            int4v af[2], bf[2];
#pragma unroll
            for (int i = 0; i < 2; ++i)
                af[i] = *(const int4v*)&Asm[(((wm * 2 + i) * 2 + ks) * 64 + lane) * 16];
#pragma unroll
            for (int j = 0; j < 2; ++j)
                bf[j] = *(const int4v*)&Bsm[(((wn * 2 + j) * 2 + ks) * 64 + lane) * 16];
#pragma unroll
            for (int i = 0; i < 2; ++i)
#pragma unroll
                for (int j = 0; j < 2; ++j)
                    acc[i][j] = __builtin_amdgcn_mfma_i32_32x32x32_i8(af[i], bf[j], acc[i][j], 0, 0, 0);
        }
        __syncthreads();
    }

    // epilogue: C/D layout col=lane&31, row=(reg&3)+8*(reg>>2)+4*(lane>>5)
    int col = lane & 31;
    int rbase = (lane >> 5) * 4;
#pragma unroll
    for (int j = 0; j < 2; ++j) {
        int cn = C0 + wn * 64 + j * 32 + col;
        float bv = __half2float(bias[cn]);
#pragma unroll
        for (int i = 0; i < 2; ++i) {
            int rm = R0 + wm * 64 + i * 32 + rbase;
#pragma unroll
            for (int reg = 0; reg < 16; ++reg) {
                int row = rm + (reg & 3) + 8 * (reg >> 2);
                C[(size_t)row * N_DIM + cn] = (float)acc[i][j][reg] + bv;
            }
        }
    }
}

extern "C" void kernel_launch(void* const* d_in, const int* in_sizes, int n_in,
                              void* d_out, int out_size, void* d_ws, size_t ws_size,
                              hipStream_t stream) {
    const int* x = (const int*)d_in[0];
    const int* wgt = (const int*)d_in[1];
    const __half* bias = (const __half*)d_in[2];
    float* out = (float*)d_out;

    char* at = (char*)d_ws;                                   // 32 MiB tiled A
    char* bt = (char*)d_ws + (size_t)M_DIM * K_DIM;           // 4 MiB tiled B^T

    pack_x_kernel<<<(M_DIM / 32) * KSEG / 2, 256, 0, stream>>>(x, at);
    wt_pack_kernel<<<(K_DIM / 64) * (N_DIM / 64), 256, 0, stream>>>(wgt, bt);
    gemm_i8_kernel<<<(M_DIM / BM) * (N_DIM / BN), 512, 0, stream>>>(at, bt, bias, out);
}